// Round 12
// baseline (135.560 us; speedup 1.0000x reference)
//
#include <hip/hip_runtime.h>

#define BB 64
#define SS 512
#define HH 1024
#define SUP 100
#define KFS 5
#define NCLS 3
#define SEG 32            // pool s-segments: 2048 blocks, 16 rows each
#define KSPLIT 8          // K-split for GEMM partials
#define KB (HH / KSPLIT)  // 128
#define KC 32             // K per LDS chunk
#define ASLD 68           // padded LDS row

#define MAC16() { \
    _Pragma("unroll") \
    for (int k = 0; k < KC; ++k) { \
        float4 a4 = *(const float4*)&As[k][tm*4]; \
        float4 b4 = *(const float4*)&Bs[k][tn*4]; \
        acc[0][0]+=a4.x*b4.x; acc[0][1]+=a4.x*b4.y; acc[0][2]+=a4.x*b4.z; acc[0][3]+=a4.x*b4.w; \
        acc[1][0]+=a4.y*b4.x; acc[1][1]+=a4.y*b4.y; acc[1][2]+=a4.y*b4.z; acc[1][3]+=a4.y*b4.w; \
        acc[2][0]+=a4.z*b4.x; acc[2][1]+=a4.z*b4.y; acc[2][2]+=a4.z*b4.z; acc[2][3]+=a4.z*b4.w; \
        acc[3][0]+=a4.w*b4.x; acc[3][1]+=a4.w*b4.y; acc[3][2]+=a4.w*b4.z; acc[3][3]+=a4.w*b4.w; } }

#define WRITE_AS(s0, s1) { \
    As[lq*4+0][lr]=s0.x; As[lq*4+1][lr]=s0.y; As[lq*4+2][lr]=s0.z; As[lq*4+3][lr]=s0.w; \
    As[16+lq*4+0][lr]=s1.x; As[16+lq*4+1][lr]=s1.y; As[16+lq*4+2][lr]=s1.z; As[16+lq*4+3][lr]=s1.w; }

#define WRITE_BS(w0, w1) { \
    Bs[lq*4+0][lr]=w0.x; Bs[lq*4+1][lr]=w0.y; Bs[lq*4+2][lr]=w0.z; Bs[lq*4+3][lr]=w0.w; \
    Bs[16+lq*4+0][lr]=w1.x; Bs[16+lq*4+1][lr]=w1.y; Bs[16+lq*4+2][lr]=w1.z; Bs[16+lq*4+3][lr]=w1.w; }

#define STORE_OUT(buf, N) { \
    _Pragma("unroll") \
    for (int i = 0; i < 4; ++i) \
        *(float4*)((buf) + ((size_t)ks*64 + tm*4 + i)*(N) + n0 + tn*4) = \
            make_float4(acc[i][0], acc[i][1], acc[i][2], acc[i][3]); }

// ======================= K1: pool partials — reg-ILP, plain loads (R6-verified best) =======================
// Streaming-read ceiling measured ~3 TB/s (reg-ILP == global_load_lds == nt-load, R6/R9/R11).
// Keep standalone: co-compiling with LDS-GEMM branches drops VGPR to ~36 and serializes
// the 16 in-flight loads (R5/R7 regression).
__global__ void pool_partial(const float* __restrict__ hs, float* __restrict__ part) {
    int blk = blockIdx.x;
    int b   = blk >> 5;
    int seg = blk & (SEG - 1);
    int t   = threadIdx.x;
    const float4* src = (const float4*)(hs + (size_t)b * SS * HH) + (size_t)(seg * 16) * 256 + t;
    float4 v[16];
#pragma unroll
    for (int i = 0; i < 16; ++i) v[i] = src[(size_t)i * 256];
#pragma unroll
    for (int st = 8; st; st >>= 1)
#pragma unroll
        for (int i = 0; i < st; ++i) {
            v[i].x += v[i + st].x; v[i].y += v[i + st].y;
            v[i].z += v[i + st].z; v[i].w += v[i + st].w;
        }
    ((float4*)part)[(size_t)(seg * BB + b) * 256 + t] = v[0];
}

// ======================= K2: reduce partials -> pooled (R6-verified) =======================
__global__ void pool_reduce(const float* __restrict__ part, float* __restrict__ pooled) {
    int b = blockIdx.x;
    int t = threadIdx.x;
    float4 acc = make_float4(0.f, 0.f, 0.f, 0.f);
#pragma unroll 4
    for (int seg = 0; seg < SEG; ++seg) {
        float4 v = ((const float4*)part)[(size_t)(seg * BB + b) * 256 + t];
        acc.x += v.x; acc.y += v.y; acc.z += v.z; acc.w += v.w;
    }
    const float inv = 1.0f / 512.0f;
    acc.x *= inv; acc.y *= inv; acc.z *= inv; acc.w *= inv;
    ((float4*)pooled)[b * 256 + t] = acc;
}

// ---------------- 64x64 K-partial GEMM tile (R6-verified) ----------------
__device__ __forceinline__ void gemm64_partial(const float* __restrict__ A,
                                               const float* __restrict__ W,
                                               float* __restrict__ partOut, int N,
                                               int n0, int k0, int ks, int t,
                                               float (*As)[ASLD], float (*Bs)[ASLD]) {
    int tm = t >> 4, tn = t & 15;
    int lr = t >> 2, lq = t & 3;
    float acc[4][4] = {};
    for (int kc = 0; kc < KB; kc += KC) {
        int ka = k0 + kc + lq * 4;
        float4 a0 = *(const float4*)(A + (size_t)lr * HH + ka);
        float4 a1 = *(const float4*)(A + (size_t)lr * HH + ka + 16);
        float4 w0 = *(const float4*)(W + (size_t)(n0 + lr) * HH + ka);
        float4 w1 = *(const float4*)(W + (size_t)(n0 + lr) * HH + ka + 16);
        WRITE_AS(a0, a1);
        WRITE_BS(w0, w1);
        __syncthreads();
        MAC16();
        __syncthreads();
    }
    STORE_OUT(partOut, N);
}

// ======================= K3: GEMM K-partials (176 blocks, R6-verified) =======================
// [0,16) sim | [16,32) div | [32,160) meta | [160,176) sims
__global__ void lin_partial(const float* __restrict__ pooled,
                            const float* __restrict__ W_sim,
                            const float* __restrict__ W_div,
                            const float* __restrict__ W_met,
                            const float* __restrict__ supF,
                            float* __restrict__ pSim, float* __restrict__ pDiv,
                            float* __restrict__ pMet, float* __restrict__ pSims) {
    __shared__ __align__(16) float As[KC][ASLD];
    __shared__ __align__(16) float Bs[KC][ASLD];
    int id = blockIdx.x, t = threadIdx.x;

    if (id < 16) {
        gemm64_partial(pooled, W_sim, pSim, 128, (id >> 3) * 64, (id & 7) * KB, id & 7, t, As, Bs);
        return;
    }
    if (id < 32) {
        int i2 = id - 16;
        gemm64_partial(pooled, W_div, pDiv, 128, (i2 >> 3) * 64, (i2 & 7) * KB, i2 & 7, t, As, Bs);
        return;
    }
    if (id < 160) {
        int i2 = id - 32;
        gemm64_partial(pooled, W_met, pMet, 1024, (i2 >> 3) * 64, (i2 & 7) * KB, i2 & 7, t, As, Bs);
        return;
    }

    // ---- sims: B row j -> pooled (j<64) else supF (clamped at 99; j>=100 garbage, never read) ----
    {
        int i2 = id - 160;
        int n0 = (i2 >> 3) * 64, ks = i2 & 7, k0 = ks * KB;
        int tm = t >> 4, tn = t & 15;
        int lr = t >> 2, lq = t & 3;
        float acc[4][4] = {};
        int j = n0 + lr;
        const float* wrow = (j < BB) ? (pooled + (size_t)j * HH)
                                     : (supF + (size_t)(j < SUP ? j : SUP - 1) * HH);
        for (int kc = 0; kc < KB; kc += KC) {
            int ka = k0 + kc + lq * 4;
            float4 a0 = *(const float4*)(pooled + (size_t)lr * HH + ka);
            float4 a1 = *(const float4*)(pooled + (size_t)lr * HH + ka + 16);
            float4 w0 = *(const float4*)(wrow + ka);
            float4 w1 = *(const float4*)(wrow + ka + 16);
            WRITE_AS(a0, a1);
            WRITE_BS(w0, w1);
            __syncthreads();
            MAC16();
            __syncthreads();
        }
        STORE_OUT(pSims, 128);
    }
}

// ======================= K4: fewshot+sim/div-combine (0..63) | full-K con (64..67) =======================
// Absorbs the old `combine` kernel: 5 -> 4 launches. fewshot blocks depend only on
// lin outputs (pSims/pSim/pDiv); con blocks depend only on lin's pMet. No intra-kernel deps.
__global__ void k4_tail(const float* __restrict__ pSims,
                        const int* __restrict__ labels,
                        const int* __restrict__ supL,
                        const float* __restrict__ pMet,
                        const float* __restrict__ b_met,
                        const float* __restrict__ W_con,
                        const float* __restrict__ b_con,
                        const float* __restrict__ pSim, const float* __restrict__ b_sim,
                        const float* __restrict__ pDiv, const float* __restrict__ b_div,
                        float* __restrict__ out_fsp, float* __restrict__ out_sim,
                        float* __restrict__ out_div, float* __restrict__ out_con) {
    __shared__ __align__(16) float As[KC][ASLD];
    __shared__ __align__(16) float Bs[KC][ASLD];
    __shared__ float simsS[128];
    __shared__ float pred[NCLS];
    int blk = blockIdx.x, t = threadIdx.x;

    if (blk >= BB) {
        // ---- con, full K (no split): A = meta_mean (sum 8 pMet partials + b_met), write final ----
        int id = blk - BB;                 // 0..3 n-tiles
        int n0 = id * 64;
        int tm = t >> 4, tn = t & 15;
        int lr = t >> 2, lq = t & 3;
        float acc[4][4] = {};
        for (int kc = 0; kc < HH; kc += KC) {
            int ka = kc + lq * 4;
            float4 s0 = *(const float4*)(b_met + ka);
            float4 s1 = *(const float4*)(b_met + ka + 16);
#pragma unroll
            for (int p = 0; p < KSPLIT; ++p) {
                float4 v0 = *(const float4*)(pMet + ((size_t)p * 64 + lr) * HH + ka);
                float4 v1 = *(const float4*)(pMet + ((size_t)p * 64 + lr) * HH + ka + 16);
                s0.x += v0.x; s0.y += v0.y; s0.z += v0.z; s0.w += v0.w;
                s1.x += v1.x; s1.y += v1.y; s1.z += v1.z; s1.w += v1.w;
            }
            float4 w0 = *(const float4*)(W_con + (size_t)(n0 + lr) * HH + ka);
            float4 w1 = *(const float4*)(W_con + (size_t)(n0 + lr) * HH + ka + 16);
            WRITE_AS(s0, s1);
            WRITE_BS(w0, w1);
            __syncthreads();
            MAC16();
            __syncthreads();
        }
        float4 bc = *(const float4*)(b_con + n0 + tn * 4);
#pragma unroll
        for (int i = 0; i < 4; ++i)
            *(float4*)(out_con + (size_t)(tm * 4 + i) * 256 + n0 + tn * 4) =
                make_float4(acc[i][0] + bc.x, acc[i][1] + bc.y,
                            acc[i][2] + bc.z, acc[i][3] + bc.w);
        return;
    }

    // ---- fewshot finalize ----
    int b = blk;
    if (t < 128) {
        float s = 0.f;
#pragma unroll
        for (int ks = 0; ks < KSPLIT; ++ks)
            s += pSims[((size_t)ks * 64 + b) * 128 + t];
        simsS[t] = s;
    }
    __syncthreads();

    if (t == 0) {
        float vals[KFS]; int idx[KFS];
        for (int i = 0; i < KFS; ++i) {
            float best = -3.4e38f; int bi = 0;
            for (int j = 0; j < SUP; ++j) {
                bool taken = false;
                for (int p = 0; p < i; ++p) taken = taken || (idx[p] == j);
                if (!taken && simsS[j] > best) { best = simsS[j]; bi = j; }
            }
            vals[i] = best; idx[i] = bi;
        }
        float mx = vals[0];
        for (int i = 1; i < KFS; ++i) mx = fmaxf(mx, vals[i]);
        float e[KFS], sum = 0.f;
        for (int i = 0; i < KFS; ++i) { e[i] = __expf(vals[i] - mx); sum += e[i]; }
        float p0 = 0.f, p1 = 0.f, p2 = 0.f;
        for (int i = 0; i < KFS; ++i) {
            int j = idx[i];
            int lab = (j < BB) ? labels[j] : supL[j];
            float wv = e[i] / sum;
            if (lab == 0) p0 += wv;
            else if (lab == 1) p1 += wv;
            else if (lab == 2) p2 += wv;
        }
        pred[0] = p0; pred[1] = p1; pred[2] = p2;
    }
    __syncthreads();

    float p[NCLS] = {pred[0], pred[1], pred[2]};
    for (int i = t; i < SS * NCLS; i += 256) {
        int c = i - (i / NCLS) * NCLS;
        out_fsp[(size_t)b * SS * NCLS + i] = p[c];
    }

    // ---- sim/div combine slice: element b*256 + t of the 16384-elem {sim|div} space ----
    {
        int i = b * 256 + t;
        if (i < 8192) {
            float s = b_sim[i & 127];
#pragma unroll
            for (int p2 = 0; p2 < KSPLIT; ++p2) s += pSim[p2 * 8192 + i];
            out_sim[i] = s;
        } else {
            int i2 = i - 8192;
            float s = b_div[i2 & 127];
#pragma unroll
            for (int p2 = 0; p2 < KSPLIT; ++p2) s += pDiv[p2 * 8192 + i2];
            out_div[i2] = s;
        }
    }
}

extern "C" void kernel_launch(void* const* d_in, const int* in_sizes, int n_in,
                              void* d_out, int out_size, void* d_ws, size_t ws_size,
                              hipStream_t stream) {
    const float* hs    = (const float*)d_in[0];
    const int*   lab   = (const int*)  d_in[1];
    const float* supF  = (const float*)d_in[2];
    const int*   supL  = (const int*)  d_in[3];
    const float* W_sim = (const float*)d_in[4];
    const float* b_sim = (const float*)d_in[5];
    const float* W_div = (const float*)d_in[6];
    const float* b_div = (const float*)d_in[7];
    const float* W_met = (const float*)d_in[8];
    const float* b_met = (const float*)d_in[9];
    const float* W_con = (const float*)d_in[10];
    const float* b_con = (const float*)d_in[11];

    float* out = (float*)d_out;
    float* out_fsp = out;                 // [64,512,3]
    float* out_sim = out + 98304;         // [64,128]
    float* out_div = out + 106496;        // [64,128]
    float* out_con = out + 114688;        // [64,256]

    float* ws     = (float*)d_ws;
    float* part   = ws;                                    // 32*64*1024 = 2M floats
    float* pooled = part + (size_t)SEG * BB * HH;          // 65,536
    float* pSim   = pooled + BB * HH;                      // 65,536
    float* pDiv   = pSim + (size_t)KSPLIT * BB * 128;      // 65,536
    float* pMet   = pDiv + (size_t)KSPLIT * BB * 128;      // 524,288
    float* pSims  = pMet + (size_t)KSPLIT * BB * HH;       // 65,536

    pool_partial<<<BB * SEG, 256, 0, stream>>>(hs, part);
    pool_reduce <<<BB,       256, 0, stream>>>(part, pooled);
    lin_partial <<<176,      256, 0, stream>>>(pooled, W_sim, W_div, W_met, supF,
                                               pSim, pDiv, pMet, pSims);
    k4_tail     <<<BB + 4,   256, 0, stream>>>(pSims, lab, supL, pMet, b_met,
                                               W_con, b_con, pSim, b_sim, pDiv, b_div,
                                               out_fsp, out_sim, out_div, out_con);
}

// Round 13
// 110.591 us; speedup vs baseline: 1.2258x; 1.2258x over previous
//
#include <hip/hip_runtime.h>

#define BB 64
#define SS 512
#define HH 1024
#define SUP 100
#define KFS 5
#define NCLS 3
#define SEG 32            // pool s-segments: 2048 blocks, 16 rows each
#define KSPLIT 8          // K-split for GEMM partials
#define KB (HH / KSPLIT)  // 128
#define KC 32             // K per LDS chunk
#define ASLD 68           // padded LDS row

#define MAC16() { \
    _Pragma("unroll") \
    for (int k = 0; k < KC; ++k) { \
        float4 a4 = *(const float4*)&As[k][tm*4]; \
        float4 b4 = *(const float4*)&Bs[k][tn*4]; \
        acc[0][0]+=a4.x*b4.x; acc[0][1]+=a4.x*b4.y; acc[0][2]+=a4.x*b4.z; acc[0][3]+=a4.x*b4.w; \
        acc[1][0]+=a4.y*b4.x; acc[1][1]+=a4.y*b4.y; acc[1][2]+=a4.y*b4.z; acc[1][3]+=a4.y*b4.w; \
        acc[2][0]+=a4.z*b4.x; acc[2][1]+=a4.z*b4.y; acc[2][2]+=a4.z*b4.z; acc[2][3]+=a4.z*b4.w; \
        acc[3][0]+=a4.w*b4.x; acc[3][1]+=a4.w*b4.y; acc[3][2]+=a4.w*b4.z; acc[3][3]+=a4.w*b4.w; } }

#define WRITE_AS(s0, s1) { \
    As[lq*4+0][lr]=s0.x; As[lq*4+1][lr]=s0.y; As[lq*4+2][lr]=s0.z; As[lq*4+3][lr]=s0.w; \
    As[16+lq*4+0][lr]=s1.x; As[16+lq*4+1][lr]=s1.y; As[16+lq*4+2][lr]=s1.z; As[16+lq*4+3][lr]=s1.w; }

#define WRITE_BS(w0, w1) { \
    Bs[lq*4+0][lr]=w0.x; Bs[lq*4+1][lr]=w0.y; Bs[lq*4+2][lr]=w0.z; Bs[lq*4+3][lr]=w0.w; \
    Bs[16+lq*4+0][lr]=w1.x; Bs[16+lq*4+1][lr]=w1.y; Bs[16+lq*4+2][lr]=w1.z; Bs[16+lq*4+3][lr]=w1.w; }

#define STORE_OUT(buf, N) { \
    _Pragma("unroll") \
    for (int i = 0; i < 4; ++i) \
        *(float4*)((buf) + ((size_t)ks*64 + tm*4 + i)*(N) + n0 + tn*4) = \
            make_float4(acc[i][0], acc[i][1], acc[i][2], acc[i][3]); }

// ======================= K1: pool partials — reg-ILP (R6-verified) =======================
// Keep standalone: co-compiling with LDS-GEMM branches drops VGPR to ~36 and serializes
// the 16 in-flight loads (R5/R7/R12 lesson).
__global__ void pool_partial(const float* __restrict__ hs, float* __restrict__ part) {
    int blk = blockIdx.x;
    int b   = blk >> 5;
    int seg = blk & (SEG - 1);
    int t   = threadIdx.x;
    const float4* src = (const float4*)(hs + (size_t)b * SS * HH) + (size_t)(seg * 16) * 256 + t;
    float4 v[16];
#pragma unroll
    for (int i = 0; i < 16; ++i) v[i] = src[(size_t)i * 256];
#pragma unroll
    for (int st = 8; st; st >>= 1)
#pragma unroll
        for (int i = 0; i < st; ++i) {
            v[i].x += v[i + st].x; v[i].y += v[i + st].y;
            v[i].z += v[i + st].z; v[i].w += v[i + st].w;
        }
    ((float4*)part)[(size_t)(seg * BB + b) * 256 + t] = v[0];
}

// ======================= K2: reduce partials -> pooled (R6-verified) =======================
__global__ void pool_reduce(const float* __restrict__ part, float* __restrict__ pooled) {
    int b = blockIdx.x;
    int t = threadIdx.x;
    float4 acc = make_float4(0.f, 0.f, 0.f, 0.f);
#pragma unroll 4
    for (int seg = 0; seg < SEG; ++seg) {
        float4 v = ((const float4*)part)[(size_t)(seg * BB + b) * 256 + t];
        acc.x += v.x; acc.y += v.y; acc.z += v.z; acc.w += v.w;
    }
    const float inv = 1.0f / 512.0f;
    acc.x *= inv; acc.y *= inv; acc.z *= inv; acc.w *= inv;
    ((float4*)pooled)[b * 256 + t] = acc;
}

// ---------------- 64x64 K-partial GEMM tile (R6-verified) ----------------
__device__ __forceinline__ void gemm64_partial(const float* __restrict__ A,
                                               const float* __restrict__ W,
                                               float* __restrict__ partOut, int N,
                                               int n0, int k0, int ks, int t,
                                               float (*As)[ASLD], float (*Bs)[ASLD]) {
    int tm = t >> 4, tn = t & 15;
    int lr = t >> 2, lq = t & 3;
    float acc[4][4] = {};
    for (int kc = 0; kc < KB; kc += KC) {
        int ka = k0 + kc + lq * 4;
        float4 a0 = *(const float4*)(A + (size_t)lr * HH + ka);
        float4 a1 = *(const float4*)(A + (size_t)lr * HH + ka + 16);
        float4 w0 = *(const float4*)(W + (size_t)(n0 + lr) * HH + ka);
        float4 w1 = *(const float4*)(W + (size_t)(n0 + lr) * HH + ka + 16);
        WRITE_AS(a0, a1);
        WRITE_BS(w0, w1);
        __syncthreads();
        MAC16();
        __syncthreads();
    }
    STORE_OUT(partOut, N);
}

// ======================= K3: GEMM K-partials (176 blocks, R6-verified) =======================
// [0,16) sim | [16,32) div | [32,160) meta | [160,176) sims
__global__ void lin_partial(const float* __restrict__ pooled,
                            const float* __restrict__ W_sim,
                            const float* __restrict__ W_div,
                            const float* __restrict__ W_met,
                            const float* __restrict__ supF,
                            float* __restrict__ pSim, float* __restrict__ pDiv,
                            float* __restrict__ pMet, float* __restrict__ pSims) {
    __shared__ __align__(16) float As[KC][ASLD];
    __shared__ __align__(16) float Bs[KC][ASLD];
    int id = blockIdx.x, t = threadIdx.x;

    if (id < 16) {
        gemm64_partial(pooled, W_sim, pSim, 128, (id >> 3) * 64, (id & 7) * KB, id & 7, t, As, Bs);
        return;
    }
    if (id < 32) {
        int i2 = id - 16;
        gemm64_partial(pooled, W_div, pDiv, 128, (i2 >> 3) * 64, (i2 & 7) * KB, i2 & 7, t, As, Bs);
        return;
    }
    if (id < 160) {
        int i2 = id - 32;
        gemm64_partial(pooled, W_met, pMet, 1024, (i2 >> 3) * 64, (i2 & 7) * KB, i2 & 7, t, As, Bs);
        return;
    }

    // ---- sims: B row j -> pooled (j<64) else supF (clamped at 99; j>=100 garbage, never read) ----
    {
        int i2 = id - 160;
        int n0 = (i2 >> 3) * 64, ks = i2 & 7, k0 = ks * KB;
        int tm = t >> 4, tn = t & 15;
        int lr = t >> 2, lq = t & 3;
        float acc[4][4] = {};
        int j = n0 + lr;
        const float* wrow = (j < BB) ? (pooled + (size_t)j * HH)
                                     : (supF + (size_t)(j < SUP ? j : SUP - 1) * HH);
        for (int kc = 0; kc < KB; kc += KC) {
            int ka = k0 + kc + lq * 4;
            float4 a0 = *(const float4*)(pooled + (size_t)lr * HH + ka);
            float4 a1 = *(const float4*)(pooled + (size_t)lr * HH + ka + 16);
            float4 w0 = *(const float4*)(wrow + ka);
            float4 w1 = *(const float4*)(wrow + ka + 16);
            WRITE_AS(a0, a1);
            WRITE_BS(w0, w1);
            __syncthreads();
            MAC16();
            __syncthreads();
        }
        STORE_OUT(pSims, 128);
    }
}

// ======================= K4: fewshot+sim/div-combine (0..63) | meta-combine (64..127) =======================
// Both halves depend only on K3 outputs; no deep load chains (max 8 independent float4s).
__global__ void k4_mid(const float* __restrict__ pSims,
                       const int* __restrict__ labels,
                       const int* __restrict__ supL,
                       const float* __restrict__ pMet,
                       const float* __restrict__ b_met,
                       const float* __restrict__ pSim, const float* __restrict__ b_sim,
                       const float* __restrict__ pDiv, const float* __restrict__ b_div,
                       float* __restrict__ meta_mean,
                       float* __restrict__ out_fsp, float* __restrict__ out_sim,
                       float* __restrict__ out_div) {
    __shared__ float simsS[128];
    __shared__ float pred[NCLS];
    int blk = blockIdx.x, t = threadIdx.x;

    if (blk >= BB) {
        // ---- meta-combine: meta_mean[b] = sum_p pMet[p][b] + b_met (pool_reduce pattern) ----
        int b = blk - BB;
        float4 acc = ((const float4*)b_met)[t];
#pragma unroll
        for (int p = 0; p < KSPLIT; ++p) {
            float4 v = ((const float4*)pMet)[(size_t)(p * BB + b) * 256 + t];
            acc.x += v.x; acc.y += v.y; acc.z += v.z; acc.w += v.w;
        }
        ((float4*)meta_mean)[(size_t)b * 256 + t] = acc;
        return;
    }

    // ---- fewshot finalize (R11-verified) ----
    int b = blk;
    if (t < 128) {
        float s = 0.f;
#pragma unroll
        for (int ks = 0; ks < KSPLIT; ++ks)
            s += pSims[((size_t)ks * 64 + b) * 128 + t];
        simsS[t] = s;
    }
    __syncthreads();

    if (t == 0) {
        float vals[KFS]; int idx[KFS];
        for (int i = 0; i < KFS; ++i) {
            float best = -3.4e38f; int bi = 0;
            for (int j = 0; j < SUP; ++j) {
                bool taken = false;
                for (int p = 0; p < i; ++p) taken = taken || (idx[p] == j);
                if (!taken && simsS[j] > best) { best = simsS[j]; bi = j; }
            }
            vals[i] = best; idx[i] = bi;
        }
        float mx = vals[0];
        for (int i = 1; i < KFS; ++i) mx = fmaxf(mx, vals[i]);
        float e[KFS], sum = 0.f;
        for (int i = 0; i < KFS; ++i) { e[i] = __expf(vals[i] - mx); sum += e[i]; }
        float p0 = 0.f, p1 = 0.f, p2 = 0.f;
        for (int i = 0; i < KFS; ++i) {
            int j = idx[i];
            int lab = (j < BB) ? labels[j] : supL[j];
            float wv = e[i] / sum;
            if (lab == 0) p0 += wv;
            else if (lab == 1) p1 += wv;
            else if (lab == 2) p2 += wv;
        }
        pred[0] = p0; pred[1] = p1; pred[2] = p2;
    }
    __syncthreads();

    float p[NCLS] = {pred[0], pred[1], pred[2]};
    for (int i = t; i < SS * NCLS; i += 256) {
        int c = i - (i / NCLS) * NCLS;
        out_fsp[(size_t)b * SS * NCLS + i] = p[c];
    }

    // ---- sim/div combine slice: element b*256 + t of the 16384-elem {sim|div} space ----
    {
        int i = b * 256 + t;
        if (i < 8192) {
            float s = b_sim[i & 127];
#pragma unroll
            for (int p2 = 0; p2 < KSPLIT; ++p2) s += pSim[p2 * 8192 + i];
            out_sim[i] = s;
        } else {
            int i2 = i - 8192;
            float s = b_div[i2 & 127];
#pragma unroll
            for (int p2 = 0; p2 < KSPLIT; ++p2) s += pDiv[p2 * 8192 + i2];
            out_div[i2] = s;
        }
    }
}

// ======================= K5: con full-K, 64x16 tiles (16 blocks), standalone =======================
// A = meta_mean (clean rows, 2 loads/chunk/thread), B rows broadcast from LDS.
// Writes out_con + b_con directly — no partials, no combine.
__global__ void k5_con(const float* __restrict__ mm,
                       const float* __restrict__ W_con,
                       const float* __restrict__ b_con,
                       float* __restrict__ out_con) {
    __shared__ __align__(16) float As[KC][ASLD];
    __shared__ __align__(16) float Bs[KC][20];   // 16 cols + pad
    int id = blockIdx.x, t = threadIdx.x;
    int n0 = id * 16;
    int r  = t & 63, cq = t >> 6;                // output row, col-quad (wave-uniform)
    int lr = t >> 2, lq = t & 3;                 // A-stage indices
    float acc0 = 0.f, acc1 = 0.f, acc2 = 0.f, acc3 = 0.f;
    for (int kc = 0; kc < HH; kc += KC) {
        int ka = kc + lq * 4;
        float4 a0 = *(const float4*)(mm + (size_t)lr * HH + ka);
        float4 a1 = *(const float4*)(mm + (size_t)lr * HH + ka + 16);
        WRITE_AS(a0, a1);
        if (t < 128) {
            int row = t & 15, kq = t >> 4;       // 16 rows x 8 k-quads
            float4 wv = *(const float4*)(W_con + (size_t)(n0 + row) * HH + kc + kq * 4);
            Bs[kq * 4 + 0][row] = wv.x; Bs[kq * 4 + 1][row] = wv.y;
            Bs[kq * 4 + 2][row] = wv.z; Bs[kq * 4 + 3][row] = wv.w;
        }
        __syncthreads();
#pragma unroll
        for (int k = 0; k < KC; ++k) {
            float a = As[k][r];                   // 64 lanes consecutive -> 2-way, free
            acc0 += a * Bs[k][cq * 4 + 0];        // cq wave-uniform -> broadcast
            acc1 += a * Bs[k][cq * 4 + 1];
            acc2 += a * Bs[k][cq * 4 + 2];
            acc3 += a * Bs[k][cq * 4 + 3];
        }
        __syncthreads();
    }
    int c = n0 + cq * 4;
    *(float4*)(out_con + (size_t)r * 256 + c) =
        make_float4(acc0 + b_con[c], acc1 + b_con[c + 1],
                    acc2 + b_con[c + 2], acc3 + b_con[c + 3]);
}

extern "C" void kernel_launch(void* const* d_in, const int* in_sizes, int n_in,
                              void* d_out, int out_size, void* d_ws, size_t ws_size,
                              hipStream_t stream) {
    const float* hs    = (const float*)d_in[0];
    const int*   lab   = (const int*)  d_in[1];
    const float* supF  = (const float*)d_in[2];
    const int*   supL  = (const int*)  d_in[3];
    const float* W_sim = (const float*)d_in[4];
    const float* b_sim = (const float*)d_in[5];
    const float* W_div = (const float*)d_in[6];
    const float* b_div = (const float*)d_in[7];
    const float* W_met = (const float*)d_in[8];
    const float* b_met = (const float*)d_in[9];
    const float* W_con = (const float*)d_in[10];
    const float* b_con = (const float*)d_in[11];

    float* out = (float*)d_out;
    float* out_fsp = out;                 // [64,512,3]
    float* out_sim = out + 98304;         // [64,128]
    float* out_div = out + 106496;        // [64,128]
    float* out_con = out + 114688;        // [64,256]

    float* ws       = (float*)d_ws;
    float* part     = ws;                                  // 2,097,152
    float* pooled   = part + (size_t)SEG * BB * HH;        // 65,536
    float* pSim     = pooled + BB * HH;                    // 65,536
    float* pDiv     = pSim + (size_t)KSPLIT * BB * 128;    // 65,536
    float* pMet     = pDiv + (size_t)KSPLIT * BB * 128;    // 524,288
    float* pSims    = pMet + (size_t)KSPLIT * BB * HH;     // 65,536
    float* meta_mean= pSims + (size_t)KSPLIT * BB * 128;   // 65,536

    pool_partial<<<BB * SEG, 256, 0, stream>>>(hs, part);
    pool_reduce <<<BB,       256, 0, stream>>>(part, pooled);
    lin_partial <<<176,      256, 0, stream>>>(pooled, W_sim, W_div, W_met, supF,
                                               pSim, pDiv, pMet, pSims);
    k4_mid      <<<2 * BB,   256, 0, stream>>>(pSims, lab, supL, pMet, b_met,
                                               pSim, b_sim, pDiv, b_div,
                                               meta_mean, out_fsp, out_sim, out_div);
    k5_con      <<<16,       256, 0, stream>>>(meta_mean, W_con, b_con, out_con);
}

// Round 14
// 104.159 us; speedup vs baseline: 1.3015x; 1.0618x over previous
//
#include <hip/hip_runtime.h>

#define BB 64
#define SS 512
#define HH 1024
#define SUP 100
#define KFS 5
#define NCLS 3
#define SEG 32            // pool s-segments: 2048 blocks, 16 rows each
#define KSPLIT 8          // K-split for lin GEMM partials
#define KB (HH / KSPLIT)  // 128
#define KC 32             // K per LDS chunk
#define ASLD 68           // padded LDS row
#define NCQ 32            // con partial count: 8 p x 4 ks

#define MAC16() { \
    _Pragma("unroll") \
    for (int k = 0; k < KC; ++k) { \
        float4 a4 = *(const float4*)&As[k][tm*4]; \
        float4 b4 = *(const float4*)&Bs[k][tn*4]; \
        acc[0][0]+=a4.x*b4.x; acc[0][1]+=a4.x*b4.y; acc[0][2]+=a4.x*b4.z; acc[0][3]+=a4.x*b4.w; \
        acc[1][0]+=a4.y*b4.x; acc[1][1]+=a4.y*b4.y; acc[1][2]+=a4.y*b4.z; acc[1][3]+=a4.y*b4.w; \
        acc[2][0]+=a4.z*b4.x; acc[2][1]+=a4.z*b4.y; acc[2][2]+=a4.z*b4.z; acc[2][3]+=a4.z*b4.w; \
        acc[3][0]+=a4.w*b4.x; acc[3][1]+=a4.w*b4.y; acc[3][2]+=a4.w*b4.z; acc[3][3]+=a4.w*b4.w; } }

#define WRITE_AS(s0, s1) { \
    As[lq*4+0][lr]=s0.x; As[lq*4+1][lr]=s0.y; As[lq*4+2][lr]=s0.z; As[lq*4+3][lr]=s0.w; \
    As[16+lq*4+0][lr]=s1.x; As[16+lq*4+1][lr]=s1.y; As[16+lq*4+2][lr]=s1.z; As[16+lq*4+3][lr]=s1.w; }

#define WRITE_BS(w0, w1) { \
    Bs[lq*4+0][lr]=w0.x; Bs[lq*4+1][lr]=w0.y; Bs[lq*4+2][lr]=w0.z; Bs[lq*4+3][lr]=w0.w; \
    Bs[16+lq*4+0][lr]=w1.x; Bs[16+lq*4+1][lr]=w1.y; Bs[16+lq*4+2][lr]=w1.z; Bs[16+lq*4+3][lr]=w1.w; }

#define STORE_OUT(buf, N) { \
    _Pragma("unroll") \
    for (int i = 0; i < 4; ++i) \
        *(float4*)((buf) + ((size_t)ks*64 + tm*4 + i)*(N) + n0 + tn*4) = \
            make_float4(acc[i][0], acc[i][1], acc[i][2], acc[i][3]); }

// ======================= K1: pool partials — reg-ILP (R6-verified) =======================
// Keep standalone: co-compiling with LDS-GEMM branches drops VGPR to ~36 and serializes
// the 16 in-flight loads (R5/R7/R12 lesson).
__global__ void pool_partial(const float* __restrict__ hs, float* __restrict__ part) {
    int blk = blockIdx.x;
    int b   = blk >> 5;
    int seg = blk & (SEG - 1);
    int t   = threadIdx.x;
    const float4* src = (const float4*)(hs + (size_t)b * SS * HH) + (size_t)(seg * 16) * 256 + t;
    float4 v[16];
#pragma unroll
    for (int i = 0; i < 16; ++i) v[i] = src[(size_t)i * 256];
#pragma unroll
    for (int st = 8; st; st >>= 1)
#pragma unroll
        for (int i = 0; i < st; ++i) {
            v[i].x += v[i + st].x; v[i].y += v[i + st].y;
            v[i].z += v[i + st].z; v[i].w += v[i + st].w;
        }
    ((float4*)part)[(size_t)(seg * BB + b) * 256 + t] = v[0];
}

// ======================= K2: reduce partials -> pooled (R6-verified) =======================
__global__ void pool_reduce(const float* __restrict__ part, float* __restrict__ pooled) {
    int b = blockIdx.x;
    int t = threadIdx.x;
    float4 acc = make_float4(0.f, 0.f, 0.f, 0.f);
#pragma unroll 4
    for (int seg = 0; seg < SEG; ++seg) {
        float4 v = ((const float4*)part)[(size_t)(seg * BB + b) * 256 + t];
        acc.x += v.x; acc.y += v.y; acc.z += v.z; acc.w += v.w;
    }
    const float inv = 1.0f / 512.0f;
    acc.x *= inv; acc.y *= inv; acc.z *= inv; acc.w *= inv;
    ((float4*)pooled)[b * 256 + t] = acc;
}

// ---------------- 64x64 K-partial GEMM tile (R6-verified) ----------------
__device__ __forceinline__ void gemm64_partial(const float* __restrict__ A,
                                               const float* __restrict__ W,
                                               float* __restrict__ partOut, int N,
                                               int n0, int k0, int ks, int t,
                                               float (*As)[ASLD], float (*Bs)[ASLD]) {
    int tm = t >> 4, tn = t & 15;
    int lr = t >> 2, lq = t & 3;
    float acc[4][4] = {};
    for (int kc = 0; kc < KB; kc += KC) {
        int ka = k0 + kc + lq * 4;
        float4 a0 = *(const float4*)(A + (size_t)lr * HH + ka);
        float4 a1 = *(const float4*)(A + (size_t)lr * HH + ka + 16);
        float4 w0 = *(const float4*)(W + (size_t)(n0 + lr) * HH + ka);
        float4 w1 = *(const float4*)(W + (size_t)(n0 + lr) * HH + ka + 16);
        WRITE_AS(a0, a1);
        WRITE_BS(w0, w1);
        __syncthreads();
        MAC16();
        __syncthreads();
    }
    STORE_OUT(partOut, N);
}

// ======================= K3: GEMM K-partials (177 blocks) =======================
// [0,16) sim | [16,32) div | [32,160) meta | [160,176) sims | 176 b_cm
__global__ void lin_partial(const float* __restrict__ pooled,
                            const float* __restrict__ W_sim,
                            const float* __restrict__ W_div,
                            const float* __restrict__ W_met,
                            const float* __restrict__ supF,
                            const float* __restrict__ W_con,
                            const float* __restrict__ b_met,
                            const float* __restrict__ b_con,
                            float* __restrict__ pSim, float* __restrict__ pDiv,
                            float* __restrict__ pMet, float* __restrict__ pSims,
                            float* __restrict__ b_cm) {
    __shared__ __align__(16) float As[KC][ASLD];
    __shared__ __align__(16) float Bs[KC][ASLD];
    int id = blockIdx.x, t = threadIdx.x;

    if (id < 16) {
        gemm64_partial(pooled, W_sim, pSim, 128, (id >> 3) * 64, (id & 7) * KB, id & 7, t, As, Bs);
        return;
    }
    if (id < 32) {
        int i2 = id - 16;
        gemm64_partial(pooled, W_div, pDiv, 128, (i2 >> 3) * 64, (i2 & 7) * KB, i2 & 7, t, As, Bs);
        return;
    }
    if (id < 160) {
        int i2 = id - 32;
        gemm64_partial(pooled, W_met, pMet, 1024, (i2 >> 3) * 64, (i2 & 7) * KB, i2 & 7, t, As, Bs);
        return;
    }
    if (id < 176) {
        // ---- sims: B row j -> pooled (j<64) else supF (clamped; j>=100 garbage, never read) ----
        int i2 = id - 160;
        int n0 = (i2 >> 3) * 64, ks = i2 & 7, k0 = ks * KB;
        int tm = t >> 4, tn = t & 15;
        int lr = t >> 2, lq = t & 3;
        float acc[4][4] = {};
        int j = n0 + lr;
        const float* wrow = (j < BB) ? (pooled + (size_t)j * HH)
                                     : (supF + (size_t)(j < SUP ? j : SUP - 1) * HH);
        for (int kc = 0; kc < KB; kc += KC) {
            int ka = k0 + kc + lq * 4;
            float4 a0 = *(const float4*)(pooled + (size_t)lr * HH + ka);
            float4 a1 = *(const float4*)(pooled + (size_t)lr * HH + ka + 16);
            float4 w0 = *(const float4*)(wrow + ka);
            float4 w1 = *(const float4*)(wrow + ka + 16);
            WRITE_AS(a0, a1);
            WRITE_BS(w0, w1);
            __syncthreads();
            MAC16();
            __syncthreads();
        }
        STORE_OUT(pSims, 128);
        return;
    }

    // ---- block 176: b_cm[o] = dot(W_con[o,:], b_met) + b_con[o] (R7/R8-verified) ----
    {
        float s = b_con[t];
        const float4* wr  = (const float4*)(W_con + (size_t)t * HH);
        const float4* bm4 = (const float4*)b_met;
#pragma unroll 8
        for (int m = 0; m < HH / 4; ++m) {
            float4 w = wr[m], bm = bm4[m];
            s += w.x * bm.x + w.y * bm.y + w.z * bm.z + w.w * bm.w;
        }
        b_cm[t] = s;
    }
}

// ======================= K4: con partials — per-p, standalone (NEW: linearity split) =======================
// out_con = sum_p (pMet[p] @ W_con^T) + b_cm. 128 blocks = n-tile(4) x p(8) x ks(4).
// A-stage reads a SINGLE pMet[p] slice (2 loads/chunk) — no 8-deep sum anywhere.
__global__ void con_partial(const float* __restrict__ pMet,
                            const float* __restrict__ W_con,
                            float* __restrict__ pCon2) {
    __shared__ __align__(16) float As[KC][ASLD];
    __shared__ __align__(16) float Bs[KC][ASLD];
    int id = blockIdx.x, t = threadIdx.x;
    int n0 = (id >> 5) * 64;           // 0..3 -> n-tile
    int p  = (id >> 2) & 7;            // pMet partial index
    int ksl= id & 3;                   // K slice 0..3 (256 wide)
    int k0 = ksl * 256;
    int q  = p * 4 + ksl;              // output partial index 0..31
    int tm = t >> 4, tn = t & 15;
    int lr = t >> 2, lq = t & 3;
    const float* A = pMet + (size_t)p * BB * HH;
    float acc[4][4] = {};
    for (int kc = 0; kc < 256; kc += KC) {
        int ka = k0 + kc + lq * 4;
        float4 a0 = *(const float4*)(A + (size_t)lr * HH + ka);
        float4 a1 = *(const float4*)(A + (size_t)lr * HH + ka + 16);
        float4 w0 = *(const float4*)(W_con + (size_t)(n0 + lr) * HH + ka);
        float4 w1 = *(const float4*)(W_con + (size_t)(n0 + lr) * HH + ka + 16);
        WRITE_AS(a0, a1);
        WRITE_BS(w0, w1);
        __syncthreads();
        MAC16();
        __syncthreads();
    }
#pragma unroll
    for (int i = 0; i < 4; ++i)
        *(float4*)(pCon2 + ((size_t)q * 64 + tm * 4 + i) * 256 + n0 + tn * 4) =
            make_float4(acc[i][0], acc[i][1], acc[i][2], acc[i][3]);
}

// ======================= K5: fewshot+sim/div (0..63) | con-combine (64..127) =======================
__global__ void k5_final(const float* __restrict__ pSims,
                         const int* __restrict__ labels,
                         const int* __restrict__ supL,
                         const float* __restrict__ pSim, const float* __restrict__ b_sim,
                         const float* __restrict__ pDiv, const float* __restrict__ b_div,
                         const float* __restrict__ pCon2, const float* __restrict__ b_cm,
                         float* __restrict__ out_fsp, float* __restrict__ out_sim,
                         float* __restrict__ out_div, float* __restrict__ out_con) {
    __shared__ float simsS[128];
    __shared__ float pred[NCLS];
    int blk = blockIdx.x, t = threadIdx.x;

    if (blk >= BB) {
        // ---- con combine: out_con[i] = b_cm[i&255] + sum_q pCon2[q][i]; flat, independent loads ----
        int i = (blk - BB) * 256 + t;            // 0..16383
        float s = b_cm[i & 255];
#pragma unroll
        for (int q = 0; q < NCQ; ++q) s += pCon2[(size_t)q * 16384 + i];
        out_con[i] = s;
        return;
    }

    // ---- fewshot finalize (R11/R13-verified) ----
    int b = blk;
    if (t < 128) {
        float s = 0.f;
#pragma unroll
        for (int ks = 0; ks < KSPLIT; ++ks)
            s += pSims[((size_t)ks * 64 + b) * 128 + t];
        simsS[t] = s;
    }
    __syncthreads();

    if (t == 0) {
        float vals[KFS]; int idx[KFS];
        for (int i = 0; i < KFS; ++i) {
            float best = -3.4e38f; int bi = 0;
            for (int j = 0; j < SUP; ++j) {
                bool taken = false;
                for (int p = 0; p < i; ++p) taken = taken || (idx[p] == j);
                if (!taken && simsS[j] > best) { best = simsS[j]; bi = j; }
            }
            vals[i] = best; idx[i] = bi;
        }
        float mx = vals[0];
        for (int i = 1; i < KFS; ++i) mx = fmaxf(mx, vals[i]);
        float e[KFS], sum = 0.f;
        for (int i = 0; i < KFS; ++i) { e[i] = __expf(vals[i] - mx); sum += e[i]; }
        float p0 = 0.f, p1 = 0.f, p2 = 0.f;
        for (int i = 0; i < KFS; ++i) {
            int j = idx[i];
            int lab = (j < BB) ? labels[j] : supL[j];
            float wv = e[i] / sum;
            if (lab == 0) p0 += wv;
            else if (lab == 1) p1 += wv;
            else if (lab == 2) p2 += wv;
        }
        pred[0] = p0; pred[1] = p1; pred[2] = p2;
    }
    __syncthreads();

    float p[NCLS] = {pred[0], pred[1], pred[2]};
    for (int i = t; i < SS * NCLS; i += 256) {
        int c = i - (i / NCLS) * NCLS;
        out_fsp[(size_t)b * SS * NCLS + i] = p[c];
    }

    // ---- sim/div combine slice: element b*256 + t of the 16384-elem {sim|div} space ----
    {
        int i = b * 256 + t;
        if (i < 8192) {
            float s = b_sim[i & 127];
#pragma unroll
            for (int p2 = 0; p2 < KSPLIT; ++p2) s += pSim[p2 * 8192 + i];
            out_sim[i] = s;
        } else {
            int i2 = i - 8192;
            float s = b_div[i2 & 127];
#pragma unroll
            for (int p2 = 0; p2 < KSPLIT; ++p2) s += pDiv[p2 * 8192 + i2];
            out_div[i2] = s;
        }
    }
}

extern "C" void kernel_launch(void* const* d_in, const int* in_sizes, int n_in,
                              void* d_out, int out_size, void* d_ws, size_t ws_size,
                              hipStream_t stream) {
    const float* hs    = (const float*)d_in[0];
    const int*   lab   = (const int*)  d_in[1];
    const float* supF  = (const float*)d_in[2];
    const int*   supL  = (const int*)  d_in[3];
    const float* W_sim = (const float*)d_in[4];
    const float* b_sim = (const float*)d_in[5];
    const float* W_div = (const float*)d_in[6];
    const float* b_div = (const float*)d_in[7];
    const float* W_met = (const float*)d_in[8];
    const float* b_met = (const float*)d_in[9];
    const float* W_con = (const float*)d_in[10];
    const float* b_con = (const float*)d_in[11];

    float* out = (float*)d_out;
    float* out_fsp = out;                 // [64,512,3]
    float* out_sim = out + 98304;         // [64,128]
    float* out_div = out + 106496;        // [64,128]
    float* out_con = out + 114688;        // [64,256]

    float* ws     = (float*)d_ws;
    float* part   = ws;                                    // 2,097,152
    float* pooled = part + (size_t)SEG * BB * HH;          // 65,536
    float* pSim   = pooled + BB * HH;                      // 65,536
    float* pDiv   = pSim + (size_t)KSPLIT * BB * 128;      // 65,536
    float* pMet   = pDiv + (size_t)KSPLIT * BB * 128;      // 524,288
    float* pSims  = pMet + (size_t)KSPLIT * BB * HH;       // 65,536
    float* pCon2  = pSims + (size_t)KSPLIT * BB * 128;     // 524,288 (32 x 64 x 256)
    float* b_cm   = pCon2 + (size_t)NCQ * BB * 256;        // 256

    pool_partial<<<BB * SEG, 256, 0, stream>>>(hs, part);
    pool_reduce <<<BB,       256, 0, stream>>>(part, pooled);
    lin_partial <<<177,      256, 0, stream>>>(pooled, W_sim, W_div, W_met, supF,
                                               W_con, b_met, b_con,
                                               pSim, pDiv, pMet, pSims, b_cm);
    con_partial <<<128,      256, 0, stream>>>(pMet, W_con, pCon2);
    k5_final    <<<2 * BB,   256, 0, stream>>>(pSims, lab, supL, pSim, b_sim,
                                               pDiv, b_div, pCon2, b_cm,
                                               out_fsp, out_sim, out_div, out_con);
}